// Round 1
// baseline (4184.028 us; speedup 1.0000x reference)
//
#include <hip/hip_runtime.h>
#include <math.h>

#define H_    16
#define S_    2048
#define HID_  2048
#define DOWN_ 512
#define UP_   1024
#define ROPE_ 64
#define MTOK  8192   // B*S

// ---------------------------------------------------------------------------
// Generic tiled fp32 GEMM:  C = A(MxK) @ W(KxN) + bias(N), with epilogue modes
// MODE 0: plain row-major C[M][N]
// MODE 1: scatter to (B,H,S,128) at col offset 0   (k_c, q_c)
// MODE 2: scatter to (B,H,S,128) at col offset 64, with RoPE(pos=s)  (q_r)
// MODE 3: scatter to (B,H,S,64)                     (v_c)
// MODE 4: N=64, RoPE(pos=s), broadcast to all 16 heads at offset 64 (k_r)
// Tile: 64x64, BK=16, 256 threads, 4x4 micro-tile.
// ---------------------------------------------------------------------------
template <int MODE>
__global__ __launch_bounds__(256) void gemm_k(const float* __restrict__ A,
                                              const float* __restrict__ W,
                                              const float* __restrict__ bias,
                                              float* __restrict__ C,
                                              int M, int N, int K) {
    __shared__ float As[16][68];   // transposed A tile [k][m], pad 68 -> <=2-way
    __shared__ float Bs[16][68];   // B tile [k][n]

    const int tid = threadIdx.x;
    const int tx = tid & 15, ty = tid >> 4;
    const int m0 = blockIdx.y * 64, n0 = blockIdx.x * 64;

    const int arow = tid >> 2;          // 0..63
    const int acol = (tid & 3) << 2;    // 0,4,8,12
    const int brow = tid >> 4;          // 0..15
    const int bcol = (tid & 15) << 2;   // 0..60

    const float* Aptr = A + (size_t)(m0 + arow) * K + acol;
    const float* Bptr = W + (size_t)brow * N + n0 + bcol;

    float acc[4][4] = {};

    for (int k0 = 0; k0 < K; k0 += 16) {
        float4 av = *(const float4*)(Aptr + k0);
        float4 bv = *(const float4*)(Bptr + (size_t)k0 * N);
        __syncthreads();
        As[acol + 0][arow] = av.x;
        As[acol + 1][arow] = av.y;
        As[acol + 2][arow] = av.z;
        As[acol + 3][arow] = av.w;
        *(float4*)&Bs[brow][bcol] = bv;
        __syncthreads();
#pragma unroll
        for (int k = 0; k < 16; ++k) {
            float4 a4 = *(float4*)&As[k][ty << 2];
            float4 b4 = *(float4*)&Bs[k][tx << 2];
            float ar[4] = {a4.x, a4.y, a4.z, a4.w};
            float br[4] = {b4.x, b4.y, b4.z, b4.w};
#pragma unroll
            for (int i = 0; i < 4; ++i)
#pragma unroll
                for (int j = 0; j < 4; ++j)
                    acc[i][j] += ar[i] * br[j];
        }
    }

    const int gm = m0 + (ty << 2);
    const int gn = n0 + (tx << 2);
    const float b0 = bias[gn], b1 = bias[gn + 1], b2 = bias[gn + 2], b3 = bias[gn + 3];

    if constexpr (MODE == 0) {
#pragma unroll
        for (int i = 0; i < 4; ++i) {
            float4 o = make_float4(acc[i][0] + b0, acc[i][1] + b1,
                                   acc[i][2] + b2, acc[i][3] + b3);
            *(float4*)&C[(size_t)(gm + i) * N + gn] = o;
        }
    } else if constexpr (MODE == 1 || MODE == 3) {
        const int h = gn >> 6, c = gn & 63;
        const int stride = (MODE == 1) ? 128 : 64;
#pragma unroll
        for (int i = 0; i < 4; ++i) {
            const int m = gm + i;
            const int b = m >> 11, s = m & 2047;
            float4 o = make_float4(acc[i][0] + b0, acc[i][1] + b1,
                                   acc[i][2] + b2, acc[i][3] + b3);
            *(float4*)&C[((size_t)(b * H_ + h) * S_ + s) * stride + c] = o;
        }
    } else if constexpr (MODE == 2) {
        const int h = gn >> 6, d0 = gn & 63;
        const int ip0 = d0 >> 1, ip1 = ip0 + 1;
        const float fr0 = powf(10000.0f, -(float)(2 * ip0) * (1.0f / 64.0f));
        const float fr1 = powf(10000.0f, -(float)(2 * ip1) * (1.0f / 64.0f));
#pragma unroll
        for (int i = 0; i < 4; ++i) {
            const int m = gm + i;
            const int b = m >> 11, s = m & 2047;
            const float pos = (float)s;
            float sn0, cs0, sn1, cs1;
            sincosf(pos * fr0, &sn0, &cs0);
            sincosf(pos * fr1, &sn1, &cs1);
            const float x0 = acc[i][0] + b0, x1 = acc[i][1] + b1;
            const float x2 = acc[i][2] + b2, x3 = acc[i][3] + b3;
            float4 o = make_float4(x0 * cs0 - x1 * sn0, x1 * cs0 + x0 * sn0,
                                   x2 * cs1 - x3 * sn1, x3 * cs1 + x2 * sn1);
            *(float4*)&C[((size_t)(b * H_ + h) * S_ + s) * 128 + 64 + d0] = o;
        }
    } else {  // MODE 4: k_r, N == 64
        const int d0 = gn;  // n0 == 0
        const int ip0 = d0 >> 1, ip1 = ip0 + 1;
        const float fr0 = powf(10000.0f, -(float)(2 * ip0) * (1.0f / 64.0f));
        const float fr1 = powf(10000.0f, -(float)(2 * ip1) * (1.0f / 64.0f));
#pragma unroll
        for (int i = 0; i < 4; ++i) {
            const int m = gm + i;
            const int b = m >> 11, s = m & 2047;
            const float pos = (float)s;
            float sn0, cs0, sn1, cs1;
            sincosf(pos * fr0, &sn0, &cs0);
            sincosf(pos * fr1, &sn1, &cs1);
            const float x0 = acc[i][0] + b0, x1 = acc[i][1] + b1;
            const float x2 = acc[i][2] + b2, x3 = acc[i][3] + b3;
            float4 o = make_float4(x0 * cs0 - x1 * sn0, x1 * cs0 + x0 * sn0,
                                   x2 * cs1 - x3 * sn1, x3 * cs1 + x2 * sn1);
            for (int h = 0; h < H_; ++h)
                *(float4*)&C[((size_t)(b * H_ + h) * S_ + s) * 128 + 64 + d0] = o;
        }
    }
}

// ---------------------------------------------------------------------------
// Flash attention (fp32, causal), TQ=32, TK=32, 256 threads.
// Q,K: (B*H, S, 128)  V: (B*H, S, 64)  O: (B, S, H*64)
// Each thread: 2 q-rows (ty*2+i); score cols tx+16j; out cols tx*4+j.
// ---------------------------------------------------------------------------
__global__ __launch_bounds__(256) void flash_kernel(const float* __restrict__ Q,
                                                    const float* __restrict__ K,
                                                    const float* __restrict__ V,
                                                    float* __restrict__ O) {
    __shared__ float Qs[32][132];
    __shared__ float Ks[32][132];
    __shared__ float Vs[32][68];
    __shared__ float Ps[32][36];

    const int tid = threadIdx.x;
    const int tx = tid & 15, ty = tid >> 4;
    const int bh = blockIdx.y;
    const int b = bh >> 4, h = bh & 15;
    const int q0 = blockIdx.x << 5;

    const float* Qb = Q + ((size_t)bh * S_ + q0) * 128;
    const float* Kb = K + (size_t)bh * S_ * 128;
    const float* Vb = V + (size_t)bh * S_ * 64;

    for (int i = tid; i < 32 * 32; i += 256) {
        const int r = i >> 5, c4 = (i & 31) << 2;
        *(float4*)&Qs[r][c4] = *(const float4*)&Qb[r * 128 + c4];
    }

    float m0r = -3e30f, m1r = -3e30f, l0 = 0.0f, l1 = 0.0f;
    float oa0[4] = {}, oa1[4] = {};
    const float scale = 0.051776695296636886f;  // 1/(sqrt(128)+sqrt(64))

    const int ktiles = (q0 >> 5) + 1;
    for (int t = 0; t < ktiles; ++t) {
        const int k0 = t << 5;
        __syncthreads();
        for (int i = tid; i < 32 * 32; i += 256) {
            const int r = i >> 5, c4 = (i & 31) << 2;
            *(float4*)&Ks[r][c4] = *(const float4*)&Kb[(k0 + r) * 128 + c4];
        }
        for (int i = tid; i < 32 * 16; i += 256) {
            const int r = i >> 4, c4 = (i & 15) << 2;
            *(float4*)&Vs[r][c4] = *(const float4*)&Vb[(k0 + r) * 64 + c4];
        }
        __syncthreads();

        float s00 = 0.f, s01 = 0.f, s10 = 0.f, s11 = 0.f;
#pragma unroll 8
        for (int d4 = 0; d4 < 32; ++d4) {
            float4 qa = *(float4*)&Qs[ty * 2][d4 << 2];
            float4 qb = *(float4*)&Qs[ty * 2 + 1][d4 << 2];
            float4 ka = *(float4*)&Ks[tx][d4 << 2];
            float4 kb = *(float4*)&Ks[tx + 16][d4 << 2];
            s00 += qa.x * ka.x + qa.y * ka.y + qa.z * ka.z + qa.w * ka.w;
            s01 += qa.x * kb.x + qa.y * kb.y + qa.z * kb.z + qa.w * kb.w;
            s10 += qb.x * ka.x + qb.y * ka.y + qb.z * ka.z + qb.w * ka.w;
            s11 += qb.x * kb.x + qb.y * kb.y + qb.z * kb.z + qb.w * kb.w;
        }

        const int qr0 = q0 + ty * 2, qr1 = qr0 + 1;
        const int kc0 = k0 + tx, kc1 = kc0 + 16;
        s00 *= scale; s01 *= scale; s10 *= scale; s11 *= scale;
        if (kc0 > qr0) s00 = -1e9f;
        if (kc1 > qr0) s01 = -1e9f;
        if (kc0 > qr1) s10 = -1e9f;
        if (kc1 > qr1) s11 = -1e9f;

        float ml0 = fmaxf(s00, s01), ml1 = fmaxf(s10, s11);
#pragma unroll
        for (int off = 8; off > 0; off >>= 1) {
            ml0 = fmaxf(ml0, __shfl_xor(ml0, off, 16));
            ml1 = fmaxf(ml1, __shfl_xor(ml1, off, 16));
        }
        const float mn0 = fmaxf(m0r, ml0), mn1 = fmaxf(m1r, ml1);
        const float a0 = expf(m0r - mn0), a1 = expf(m1r - mn1);
        m0r = mn0; m1r = mn1;

        const float p00 = expf(s00 - mn0), p01 = expf(s01 - mn0);
        const float p10 = expf(s10 - mn1), p11 = expf(s11 - mn1);
        Ps[ty * 2][tx] = p00;
        Ps[ty * 2][tx + 16] = p01;
        Ps[ty * 2 + 1][tx] = p10;
        Ps[ty * 2 + 1][tx + 16] = p11;

        float rs0 = p00 + p01, rs1 = p10 + p11;
#pragma unroll
        for (int off = 8; off > 0; off >>= 1) {
            rs0 += __shfl_xor(rs0, off, 16);
            rs1 += __shfl_xor(rs1, off, 16);
        }
        l0 = l0 * a0 + rs0;
        l1 = l1 * a1 + rs1;
#pragma unroll
        for (int j = 0; j < 4; ++j) { oa0[j] *= a0; oa1[j] *= a1; }
        __syncthreads();

#pragma unroll 4
        for (int k4 = 0; k4 < 8; ++k4) {
            float4 pa = *(float4*)&Ps[ty * 2][k4 << 2];
            float4 pb = *(float4*)&Ps[ty * 2 + 1][k4 << 2];
            float4 v0 = *(float4*)&Vs[(k4 << 2) + 0][tx << 2];
            float4 v1 = *(float4*)&Vs[(k4 << 2) + 1][tx << 2];
            float4 v2 = *(float4*)&Vs[(k4 << 2) + 2][tx << 2];
            float4 v3 = *(float4*)&Vs[(k4 << 2) + 3][tx << 2];
            oa0[0] += pa.x * v0.x + pa.y * v1.x + pa.z * v2.x + pa.w * v3.x;
            oa0[1] += pa.x * v0.y + pa.y * v1.y + pa.z * v2.y + pa.w * v3.y;
            oa0[2] += pa.x * v0.z + pa.y * v1.z + pa.z * v2.z + pa.w * v3.z;
            oa0[3] += pa.x * v0.w + pa.y * v1.w + pa.z * v2.w + pa.w * v3.w;
            oa1[0] += pb.x * v0.x + pb.y * v1.x + pb.z * v2.x + pb.w * v3.x;
            oa1[1] += pb.x * v0.y + pb.y * v1.y + pb.z * v2.y + pb.w * v3.y;
            oa1[2] += pb.x * v0.z + pb.y * v1.z + pb.z * v2.z + pb.w * v3.z;
            oa1[3] += pb.x * v0.w + pb.y * v1.w + pb.z * v2.w + pb.w * v3.w;
        }
    }

    const float il0 = 1.0f / l0, il1 = 1.0f / l1;
    const size_t ob = ((size_t)b * S_ + q0 + ty * 2) * (size_t)(H_ * 64) + h * 64 + (tx << 2);
    float4 o0 = make_float4(oa0[0] * il0, oa0[1] * il0, oa0[2] * il0, oa0[3] * il0);
    float4 o1 = make_float4(oa1[0] * il1, oa1[1] * il1, oa1[2] * il1, oa1[3] * il1);
    *(float4*)&O[ob] = o0;
    *(float4*)&O[ob + H_ * 64] = o1;
}

// ---------------------------------------------------------------------------
extern "C" void kernel_launch(void* const* d_in, const int* in_sizes, int n_in,
                              void* d_out, int out_size, void* d_ws, size_t ws_size,
                              hipStream_t stream) {
    const float* X     = (const float*)d_in[0];
    // d_in[1] = mask (causal tril) -- implemented analytically
    const float* W_dkv = (const float*)d_in[2];
    const float* b_dkv = (const float*)d_in[3];
    const float* W_dq  = (const float*)d_in[4];
    const float* b_dq  = (const float*)d_in[5];
    const float* W_uk  = (const float*)d_in[6];
    const float* b_uk  = (const float*)d_in[7];
    const float* W_uv  = (const float*)d_in[8];
    const float* b_uv  = (const float*)d_in[9];
    const float* W_uq  = (const float*)d_in[10];
    const float* b_uq  = (const float*)d_in[11];
    const float* W_qr  = (const float*)d_in[12];
    const float* b_qr  = (const float*)d_in[13];
    const float* W_kr  = (const float*)d_in[14];
    const float* b_kr  = (const float*)d_in[15];
    const float* W_fc  = (const float*)d_in[16];
    const float* b_fc  = (const float*)d_in[17];
    float* out = (float*)d_out;

    float* ws  = (float*)d_ws;
    float* ckv = ws;                    // 8192*512          = 4,194,304
    float* cq  = ws + 4194304;          // 4,194,304
    float* Qb  = ws + 8388608;          // (B*H,S,128)       = 16,777,216
    float* Kb  = Qb + 16777216;         // 16,777,216
    float* Vb  = Kb + 16777216;         // (B*H,S,64)        = 8,388,608
    float* attn = ws;                   // (B,S,1024) reuses dead ckv+cq region

    const dim3 blk(256);
    // c_kv = X @ W_dkv + b ; c_q = X @ W_dq + b
    gemm_k<0><<<dim3(8, 128), blk, 0, stream>>>(X, W_dkv, b_dkv, ckv, MTOK, 512, 2048);
    gemm_k<0><<<dim3(8, 128), blk, 0, stream>>>(X, W_dq, b_dq, cq, MTOK, 512, 2048);
    // k_c -> K[.., :64] ; v_c -> V ; q_c -> Q[.., :64] ; q_r -> rope -> Q[.., 64:]
    gemm_k<1><<<dim3(16, 128), blk, 0, stream>>>(ckv, W_uk, b_uk, Kb, MTOK, 1024, 512);
    gemm_k<3><<<dim3(16, 128), blk, 0, stream>>>(ckv, W_uv, b_uv, Vb, MTOK, 1024, 512);
    gemm_k<1><<<dim3(16, 128), blk, 0, stream>>>(cq, W_uq, b_uq, Qb, MTOK, 1024, 512);
    gemm_k<2><<<dim3(16, 128), blk, 0, stream>>>(cq, W_qr, b_qr, Qb, MTOK, 1024, 512);
    // k_r -> rope -> broadcast to K[.., 64:] for all 16 heads
    gemm_k<4><<<dim3(1, 128), blk, 0, stream>>>(X, W_kr, b_kr, Kb, MTOK, 64, 2048);
    // causal flash attention -> attn (B,S,1024)
    flash_kernel<<<dim3(64, 64), blk, 0, stream>>>(Qb, Kb, Vb, attn);
    // out = attn @ W_fc + b_fc
    gemm_k<0><<<dim3(32, 128), blk, 0, stream>>>(attn, W_fc, b_fc, out, MTOK, 2048, 1024);
}

// Round 2
// 2001.490 us; speedup vs baseline: 2.0905x; 2.0905x over previous
//
#include <hip/hip_runtime.h>
#include <math.h>

#define H_    16
#define S_    2048
#define HID_  2048
#define DOWN_ 512
#define UP_   1024
#define ROPE_ 64
#define MTOK  8192   // B*S

typedef __bf16 bf16_t;
typedef bf16_t bf16x4 __attribute__((ext_vector_type(4)));
typedef bf16_t bf16x8 __attribute__((ext_vector_type(8)));
typedef float  f32x4  __attribute__((ext_vector_type(4)));

__device__ inline f32x4 mfma16(bf16x8 a, bf16x8 b, f32x4 c) {
    return __builtin_amdgcn_mfma_f32_16x16x32_bf16(a, b, c, 0, 0, 0);
}

// ---------------------------------------------------------------------------
// Tiled fp32 GEMM:  C = A(MxK) @ W(KxN) + bias(N), epilogue modes:
// MODE 0: plain fp32 row-major C[M][N]
// MODE 1: bf16 scatter to (B*H,S,128) at col offset 0     (k_c, q_c)
// MODE 2: bf16 scatter to (B*H,S,128) at offset 64 + RoPE (q_r)
// MODE 3: bf16 scatter TRANSPOSED to (B*H,64,S)           (v_c -> V^T)
// MODE 4: bf16, N=64, RoPE, broadcast to 16 heads at offset 64 (k_r)
// ---------------------------------------------------------------------------
template <int MODE>
__global__ __launch_bounds__(256) void gemm_k(const float* __restrict__ A,
                                              const float* __restrict__ W,
                                              const float* __restrict__ bias,
                                              void* __restrict__ Cv,
                                              int M, int N, int K) {
    __shared__ float As[16][68];
    __shared__ float Bs[16][68];

    const int tid = threadIdx.x;
    const int tx = tid & 15, ty = tid >> 4;
    const int m0 = blockIdx.y * 64, n0 = blockIdx.x * 64;

    const int arow = tid >> 2;
    const int acol = (tid & 3) << 2;
    const int brow = tid >> 4;
    const int bcol = (tid & 15) << 2;

    const float* Aptr = A + (size_t)(m0 + arow) * K + acol;
    const float* Bptr = W + (size_t)brow * N + n0 + bcol;

    float acc[4][4] = {};

    for (int k0 = 0; k0 < K; k0 += 16) {
        float4 av = *(const float4*)(Aptr + k0);
        float4 bv = *(const float4*)(Bptr + (size_t)k0 * N);
        __syncthreads();
        As[acol + 0][arow] = av.x;
        As[acol + 1][arow] = av.y;
        As[acol + 2][arow] = av.z;
        As[acol + 3][arow] = av.w;
        *(float4*)&Bs[brow][bcol] = bv;
        __syncthreads();
#pragma unroll
        for (int k = 0; k < 16; ++k) {
            float4 a4 = *(float4*)&As[k][ty << 2];
            float4 b4 = *(float4*)&Bs[k][tx << 2];
            float ar[4] = {a4.x, a4.y, a4.z, a4.w};
            float br[4] = {b4.x, b4.y, b4.z, b4.w};
#pragma unroll
            for (int i = 0; i < 4; ++i)
#pragma unroll
                for (int j = 0; j < 4; ++j)
                    acc[i][j] += ar[i] * br[j];
        }
    }

    const int gm = m0 + (ty << 2);
    const int gn = n0 + (tx << 2);
    const float b0 = bias[gn], b1 = bias[gn + 1], b2 = bias[gn + 2], b3 = bias[gn + 3];

    if constexpr (MODE == 0) {
        float* C = (float*)Cv;
#pragma unroll
        for (int i = 0; i < 4; ++i) {
            float4 o = make_float4(acc[i][0] + b0, acc[i][1] + b1,
                                   acc[i][2] + b2, acc[i][3] + b3);
            *(float4*)&C[(size_t)(gm + i) * N + gn] = o;
        }
    } else if constexpr (MODE == 1) {
        bf16_t* C = (bf16_t*)Cv;
        const int h = gn >> 6, c = gn & 63;
#pragma unroll
        for (int i = 0; i < 4; ++i) {
            const int m = gm + i;
            const int b = m >> 11, s = m & 2047;
            bf16x4 o = {(bf16_t)(acc[i][0] + b0), (bf16_t)(acc[i][1] + b1),
                        (bf16_t)(acc[i][2] + b2), (bf16_t)(acc[i][3] + b3)};
            *(bf16x4*)&C[((size_t)(b * H_ + h) * S_ + s) * 128 + c] = o;
        }
    } else if constexpr (MODE == 2) {
        bf16_t* C = (bf16_t*)Cv;
        const int h = gn >> 6, d0 = gn & 63;
        const int ip0 = d0 >> 1, ip1 = ip0 + 1;
        const float fr0 = powf(10000.0f, -(float)(2 * ip0) * (1.0f / 64.0f));
        const float fr1 = powf(10000.0f, -(float)(2 * ip1) * (1.0f / 64.0f));
#pragma unroll
        for (int i = 0; i < 4; ++i) {
            const int m = gm + i;
            const int b = m >> 11, s = m & 2047;
            const float pos = (float)s;
            float sn0, cs0, sn1, cs1;
            sincosf(pos * fr0, &sn0, &cs0);
            sincosf(pos * fr1, &sn1, &cs1);
            const float x0 = acc[i][0] + b0, x1 = acc[i][1] + b1;
            const float x2 = acc[i][2] + b2, x3 = acc[i][3] + b3;
            bf16x4 o = {(bf16_t)(x0 * cs0 - x1 * sn0), (bf16_t)(x1 * cs0 + x0 * sn0),
                        (bf16_t)(x2 * cs1 - x3 * sn1), (bf16_t)(x3 * cs1 + x2 * sn1)};
            *(bf16x4*)&C[((size_t)(b * H_ + h) * S_ + s) * 128 + 64 + d0] = o;
        }
    } else if constexpr (MODE == 3) {
        // V^T: (B*H, 64, S); cols gn..gn+3 are vd, rows gm..gm+3 are s (consec)
        bf16_t* C = (bf16_t*)Cv;
        const int h = gn >> 6, vd = gn & 63;
        const int b = gm >> 11, s0 = gm & 2047;
        const float bb[4] = {b0, b1, b2, b3};
#pragma unroll
        for (int j = 0; j < 4; ++j) {
            bf16x4 o = {(bf16_t)(acc[0][j] + bb[j]), (bf16_t)(acc[1][j] + bb[j]),
                        (bf16_t)(acc[2][j] + bb[j]), (bf16_t)(acc[3][j] + bb[j])};
            *(bf16x4*)&C[((size_t)(b * H_ + h) * 64 + vd + j) * S_ + s0] = o;
        }
    } else {  // MODE 4: k_r, N == 64, broadcast to 16 heads
        bf16_t* C = (bf16_t*)Cv;
        const int d0 = gn;
        const int ip0 = d0 >> 1, ip1 = ip0 + 1;
        const float fr0 = powf(10000.0f, -(float)(2 * ip0) * (1.0f / 64.0f));
        const float fr1 = powf(10000.0f, -(float)(2 * ip1) * (1.0f / 64.0f));
#pragma unroll
        for (int i = 0; i < 4; ++i) {
            const int m = gm + i;
            const int b = m >> 11, s = m & 2047;
            const float pos = (float)s;
            float sn0, cs0, sn1, cs1;
            sincosf(pos * fr0, &sn0, &cs0);
            sincosf(pos * fr1, &sn1, &cs1);
            const float x0 = acc[i][0] + b0, x1 = acc[i][1] + b1;
            const float x2 = acc[i][2] + b2, x3 = acc[i][3] + b3;
            bf16x4 o = {(bf16_t)(x0 * cs0 - x1 * sn0), (bf16_t)(x1 * cs0 + x0 * sn0),
                        (bf16_t)(x2 * cs1 - x3 * sn1), (bf16_t)(x3 * cs1 + x2 * sn1)};
            for (int h = 0; h < H_; ++h)
                *(bf16x4*)&C[((size_t)(b * H_ + h) * S_ + s) * 128 + 64 + d0] = o;
        }
    }
}

// ---------------------------------------------------------------------------
// MFMA flash attention (bf16 inputs, fp32 softmax/acc), causal.
// Q,K: (B*H, S, 128) bf16; Vt: (B*H, 64, S) bf16; O: (B, S, H*64) fp32.
// Block: 256 thr = 4 waves, 64 q-rows (16/wave). K-tile = 32 keys.
// QK^T: A=Q (m=lane&15 -> q-row), B=K (n=lane&15 -> key), k = quad*8+j -> d.
// S in C-layout (col=key=lane&15, row=q=quad*4+reg); softmax row stats via
// shfl_xor(1,2,4,8); P -> LDS -> A-layout fragments for PV.
// ---------------------------------------------------------------------------
__global__ __launch_bounds__(256) void flash_mfma(const bf16_t* __restrict__ Q,
                                                  const bf16_t* __restrict__ K,
                                                  const bf16_t* __restrict__ Vt,
                                                  float* __restrict__ O) {
    __shared__ bf16_t Ks[32][136];    // 32 keys x 128 d, stride 136 (16B-aligned)
    __shared__ bf16_t Vs[64][40];     // 64 vd x 32 keys
    __shared__ bf16_t Ps[4][16][40];  // per-wave P: 16 q x 32 keys

    const int tid  = threadIdx.x;
    const int lane = tid & 63;
    const int wave = tid >> 6;
    const int n16  = lane & 15;
    const int quad = lane >> 4;
    const int bh   = blockIdx.y;
    const int q0   = blockIdx.x << 6;
    const int qbase = q0 + wave * 16;

    // preload Q fragments (4 chunks of k=32)
    const bf16_t* Qg = Q + ((size_t)bh * S_ + qbase + n16) * 128;
    bf16x8 qf[4];
#pragma unroll
    for (int c = 0; c < 4; ++c)
        qf[c] = *(const bf16x8*)(Qg + c * 32 + quad * 8);

    const bf16_t* Kg = K + (size_t)bh * S_ * 128;
    const bf16_t* Vg = Vt + (size_t)bh * 64 * S_;

    f32x4 oacc[4] = {};
    float mrow[4] = {-3e30f, -3e30f, -3e30f, -3e30f};
    float lrow[4] = {};
    const float scale = 0.051776695296636886f;  // 1/(sqrt(128)+sqrt(64))

    const int ktiles = (q0 >> 5) + 2;
    for (int t = 0; t < ktiles; ++t) {
        const int k0 = t << 5;
        __syncthreads();
        // stage K tile: 32x128 bf16 (512 chunks of 8)
#pragma unroll
        for (int c = 0; c < 2; ++c) {
            const int idx = tid + c * 256;
            const int r = idx >> 4, col = (idx & 15) << 3;
            *(bf16x8*)&Ks[r][col] = *(const bf16x8*)&Kg[(size_t)(k0 + r) * 128 + col];
        }
        // stage V^T tile: 64x32 bf16 (256 chunks of 8)
        {
            const int r = tid >> 2, col = (tid & 3) << 3;
            *(bf16x8*)&Vs[r][col] = *(const bf16x8*)&Vg[(size_t)r * S_ + k0 + col];
        }
        __syncthreads();

        // S = Q K^T for this wave's 16 q-rows x 32 keys
        f32x4 sacc0 = {}, sacc1 = {};
#pragma unroll
        for (int c = 0; c < 4; ++c) {
            bf16x8 kb0 = *(bf16x8*)&Ks[n16][c * 32 + quad * 8];
            bf16x8 kb1 = *(bf16x8*)&Ks[n16 + 16][c * 32 + quad * 8];
            sacc0 = mfma16(qf[c], kb0, sacc0);
            sacc1 = mfma16(qf[c], kb1, sacc1);
        }

        float p0[4], p1[4];
        const bool boundary = (k0 + 31 > qbase);
#pragma unroll
        for (int r = 0; r < 4; ++r) {
            float s0 = sacc0[r] * scale;
            float s1 = sacc1[r] * scale;
            if (boundary) {
                const int qrow = qbase + quad * 4 + r;
                if (k0 + n16 > qrow)      s0 = -3e30f;
                if (k0 + 16 + n16 > qrow) s1 = -3e30f;
            }
            p0[r] = s0;
            p1[r] = s1;
        }

        float alpha[4];
#pragma unroll
        for (int r = 0; r < 4; ++r) {
            float mx = fmaxf(p0[r], p1[r]);
            mx = fmaxf(mx, __shfl_xor(mx, 1));
            mx = fmaxf(mx, __shfl_xor(mx, 2));
            mx = fmaxf(mx, __shfl_xor(mx, 4));
            mx = fmaxf(mx, __shfl_xor(mx, 8));
            const float mn = fmaxf(mrow[r], mx);
            alpha[r] = __expf(mrow[r] - mn);
            mrow[r] = mn;
            const float e0 = __expf(p0[r] - mn);
            const float e1 = __expf(p1[r] - mn);
            p0[r] = e0;
            p1[r] = e1;
            float rs = e0 + e1;
            rs += __shfl_xor(rs, 1);
            rs += __shfl_xor(rs, 2);
            rs += __shfl_xor(rs, 4);
            rs += __shfl_xor(rs, 8);
            lrow[r] = lrow[r] * alpha[r] + rs;
        }
#pragma unroll
        for (int nt = 0; nt < 4; ++nt)
#pragma unroll
            for (int r = 0; r < 4; ++r)
                oacc[nt][r] *= alpha[r];

        // P: C-layout -> LDS -> A-layout
#pragma unroll
        for (int r = 0; r < 4; ++r) {
            Ps[wave][quad * 4 + r][n16]      = (bf16_t)p0[r];
            Ps[wave][quad * 4 + r][n16 + 16] = (bf16_t)p1[r];
        }
        bf16x8 pf = *(bf16x8*)&Ps[wave][n16][quad * 8];
#pragma unroll
        for (int nt = 0; nt < 4; ++nt) {
            bf16x8 vb = *(bf16x8*)&Vs[nt * 16 + n16][quad * 8];
            oacc[nt] = mfma16(pf, vb, oacc[nt]);
        }
    }

    float il[4];
#pragma unroll
    for (int r = 0; r < 4; ++r) il[r] = 1.0f / lrow[r];

    const int b = bh >> 4, h = bh & 15;
#pragma unroll
    for (int nt = 0; nt < 4; ++nt)
#pragma unroll
        for (int r = 0; r < 4; ++r)
            O[((size_t)b * S_ + qbase + quad * 4 + r) * (size_t)(H_ * 64)
              + h * 64 + nt * 16 + n16] = oacc[nt][r] * il[r];
}

// ---------------------------------------------------------------------------
extern "C" void kernel_launch(void* const* d_in, const int* in_sizes, int n_in,
                              void* d_out, int out_size, void* d_ws, size_t ws_size,
                              hipStream_t stream) {
    const float* X     = (const float*)d_in[0];
    const float* W_dkv = (const float*)d_in[2];
    const float* b_dkv = (const float*)d_in[3];
    const float* W_dq  = (const float*)d_in[4];
    const float* b_dq  = (const float*)d_in[5];
    const float* W_uk  = (const float*)d_in[6];
    const float* b_uk  = (const float*)d_in[7];
    const float* W_uv  = (const float*)d_in[8];
    const float* b_uv  = (const float*)d_in[9];
    const float* W_uq  = (const float*)d_in[10];
    const float* b_uq  = (const float*)d_in[11];
    const float* W_qr  = (const float*)d_in[12];
    const float* b_qr  = (const float*)d_in[13];
    const float* W_kr  = (const float*)d_in[14];
    const float* b_kr  = (const float*)d_in[15];
    const float* W_fc  = (const float*)d_in[16];
    const float* b_fc  = (const float*)d_in[17];
    float* out = (float*)d_out;

    float* ws  = (float*)d_ws;
    float* ckv = ws;                         // 8192*512 fp32
    float* cq  = ws + 4194304;               // 8192*512 fp32
    float* attn = ws;                        // (B,S,1024) fp32, reuses ckv+cq
    bf16_t* Qb = (bf16_t*)(ws + 8388608);    // (B*H,S,128) bf16 = 16,777,216
    bf16_t* Kb = (bf16_t*)(ws + 16777216);   // (B*H,S,128) bf16
    bf16_t* Vt = (bf16_t*)(ws + 25165824);   // (B*H,64,S)  bf16 =  8,388,608

    const dim3 blk(256);
    gemm_k<0><<<dim3(8, 128), blk, 0, stream>>>(X, W_dkv, b_dkv, ckv, MTOK, 512, 2048);
    gemm_k<0><<<dim3(8, 128), blk, 0, stream>>>(X, W_dq, b_dq, cq, MTOK, 512, 2048);
    gemm_k<1><<<dim3(16, 128), blk, 0, stream>>>(ckv, W_uk, b_uk, Kb, MTOK, 1024, 512);
    gemm_k<3><<<dim3(16, 128), blk, 0, stream>>>(ckv, W_uv, b_uv, Vt, MTOK, 1024, 512);
    gemm_k<1><<<dim3(16, 128), blk, 0, stream>>>(cq, W_uq, b_uq, Qb, MTOK, 1024, 512);
    gemm_k<2><<<dim3(16, 128), blk, 0, stream>>>(cq, W_qr, b_qr, Qb, MTOK, 1024, 512);
    gemm_k<4><<<dim3(1, 128), blk, 0, stream>>>(X, W_kr, b_kr, Kb, MTOK, 64, 2048);
    flash_mfma<<<dim3(32, 64), blk, 0, stream>>>(Qb, Kb, Vt, attn);
    gemm_k<0><<<dim3(32, 128), blk, 0, stream>>>(attn, W_fc, b_fc, out, MTOK, 2048, 1024);
}

// Round 3
// 1072.435 us; speedup vs baseline: 3.9014x; 1.8663x over previous
//
#include <hip/hip_runtime.h>
#include <math.h>

#define H_    16
#define S_    2048
#define MTOK  8192   // B*S

typedef __bf16 bf16_t;
typedef bf16_t bf16x4 __attribute__((ext_vector_type(4)));
typedef bf16_t bf16x8 __attribute__((ext_vector_type(8)));
typedef float  f32x4  __attribute__((ext_vector_type(4)));

__device__ inline f32x4 mfma16(bf16x8 a, bf16x8 b, f32x4 c) {
    return __builtin_amdgcn_mfma_f32_16x16x32_bf16(a, b, c, 0, 0, 0);
}

// async global->LDS, 16B per lane; lds pointer must be wave-uniform
#define GLOAD_LDS(gp, lp)                                                      \
    __builtin_amdgcn_global_load_lds(                                          \
        (const __attribute__((address_space(1))) void*)(gp),                   \
        (__attribute__((address_space(3))) void*)(lp), 16, 0, 0)

// ---------------------------------------------------------------------------
// cast fp32 -> bf16 (n multiple of 4)
// ---------------------------------------------------------------------------
__global__ __launch_bounds__(256) void cast_bf16(const float* __restrict__ in,
                                                 bf16_t* __restrict__ out, int n) {
    const int i = (blockIdx.x * 256 + threadIdx.x) * 4;
    if (i < n) {
        float4 v = *(const float4*)&in[i];
        bf16x4 o = {(bf16_t)v.x, (bf16_t)v.y, (bf16_t)v.z, (bf16_t)v.w};
        *(bf16x4*)&out[i] = o;
    }
}

// ---------------------------------------------------------------------------
// W (KxN fp32) -> Wt (NxK bf16). 32x32 tiles, 256 threads.
// ---------------------------------------------------------------------------
__global__ __launch_bounds__(256) void transpose_cast(const float* __restrict__ W,
                                                      bf16_t* __restrict__ Wt,
                                                      int K, int N) {
    __shared__ float t[32][33];
    const int x = threadIdx.x & 31, y = threadIdx.x >> 5;  // y: 0..7
    const int k0 = blockIdx.y * 32, n0 = blockIdx.x * 32;
#pragma unroll
    for (int j = 0; j < 4; ++j)
        t[y + j * 8][x] = W[(size_t)(k0 + y + j * 8) * N + n0 + x];
    __syncthreads();
#pragma unroll
    for (int j = 0; j < 4; ++j)
        Wt[(size_t)(n0 + y + j * 8) * K + k0 + x] = (bf16_t)t[x][y + j * 8];
}

// ---------------------------------------------------------------------------
// MFMA GEMM: C = A(MxK,bf16) @ Bt(NxK,bf16)^T + bias. 128x128 tile, BK=32,
// 256 thr = 4 waves (2x2), 16 mfma_16x16x32 per wave per K-step,
// global_load_lds width-16 staging (m97 structure).
// EP 0: bf16 row-major      EP 1: bf16 scatter (B*H,S,128) col 0..63
// EP 2: bf16 scatter offset 64 + RoPE   EP 3: bf16 V^T (B*H,64,S)
// EP 5: fp32 row-major
// ---------------------------------------------------------------------------
template <int EP>
__global__ __launch_bounds__(256) void mgemm(const bf16_t* __restrict__ A,
                                             const bf16_t* __restrict__ Bt,
                                             const float* __restrict__ bias,
                                             void* __restrict__ Cv,
                                             int M, int N, int K) {
    __shared__ bf16_t As[4096];  // 128 rows x 32 k
    __shared__ bf16_t Bs[4096];  // 128 cols x 32 k

    const int tid = threadIdx.x;
    const int lane = tid & 63, wave = tid >> 6;
    const int n16 = lane & 15, quad = lane >> 4;
    const int wm = wave & 1, wn = wave >> 1;
    const int m0 = blockIdx.y * 128, n0 = blockIdx.x * 128;

    const int crow = tid >> 2, ccol = (tid & 3) * 8;
    const bf16_t* Ag0 = A + (size_t)(m0 + crow) * K + ccol;
    const bf16_t* Ag1 = A + (size_t)(m0 + crow + 64) * K + ccol;
    const bf16_t* Bg0 = Bt + (size_t)(n0 + crow) * K + ccol;
    const bf16_t* Bg1 = Bt + (size_t)(n0 + crow + 64) * K + ccol;
    bf16_t* Al0 = As + wave * 512;
    bf16_t* Al1 = As + 2048 + wave * 512;
    bf16_t* Bl0 = Bs + wave * 512;
    bf16_t* Bl1 = Bs + 2048 + wave * 512;

    f32x4 acc[4][4] = {};

    for (int k0 = 0; k0 < K; k0 += 32) {
        GLOAD_LDS(Ag0 + k0, Al0);
        GLOAD_LDS(Ag1 + k0, Al1);
        GLOAD_LDS(Bg0 + k0, Bl0);
        GLOAD_LDS(Bg1 + k0, Bl1);
        __syncthreads();   // drains global_load_lds (vmcnt0) + protects reads
        bf16x8 af[4], bfr[4];
#pragma unroll
        for (int mt = 0; mt < 4; ++mt)
            af[mt] = *(const bf16x8*)&As[(wm * 64 + mt * 16 + n16) * 32 + quad * 8];
#pragma unroll
        for (int nt = 0; nt < 4; ++nt)
            bfr[nt] = *(const bf16x8*)&Bs[(wn * 64 + nt * 16 + n16) * 32 + quad * 8];
#pragma unroll
        for (int mt = 0; mt < 4; ++mt)
#pragma unroll
            for (int nt = 0; nt < 4; ++nt)
                acc[mt][nt] = mfma16(af[mt], bfr[nt], acc[mt][nt]);
        __syncthreads();   // protect LDS overwrite next iter
    }

    const int mbase = m0 + wm * 64;
    const int nbase = n0 + wn * 64;
#pragma unroll
    for (int nt = 0; nt < 4; ++nt) {
        const int n = nbase + nt * 16 + n16;
        const float bv = bias[n];
        if constexpr (EP == 0) {
            bf16_t* C = (bf16_t*)Cv;
#pragma unroll
            for (int mt = 0; mt < 4; ++mt)
#pragma unroll
                for (int r = 0; r < 4; ++r) {
                    const int m = mbase + mt * 16 + quad * 4 + r;
                    C[(size_t)m * N + n] = (bf16_t)(acc[mt][nt][r] + bv);
                }
        } else if constexpr (EP == 5) {
            float* C = (float*)Cv;
#pragma unroll
            for (int mt = 0; mt < 4; ++mt)
#pragma unroll
                for (int r = 0; r < 4; ++r) {
                    const int m = mbase + mt * 16 + quad * 4 + r;
                    C[(size_t)m * N + n] = acc[mt][nt][r] + bv;
                }
        } else if constexpr (EP == 1) {
            bf16_t* C = (bf16_t*)Cv;
            const int h = n >> 6, c = n & 63;
#pragma unroll
            for (int mt = 0; mt < 4; ++mt)
#pragma unroll
                for (int r = 0; r < 4; ++r) {
                    const int m = mbase + mt * 16 + quad * 4 + r;
                    const int b = m >> 11, s = m & 2047;
                    C[((size_t)(b * H_ + h) * S_ + s) * 128 + c] =
                        (bf16_t)(acc[mt][nt][r] + bv);
                }
        } else if constexpr (EP == 2) {
            bf16_t* C = (bf16_t*)Cv;
            const int h = n >> 6, d = n & 63;
            // inv_freq = 10000^(-(d&~1)/64) = 2^(-(d>>1)*log2(1e4)/32)
            const float fr = exp2f(-(float)(d >> 1) * 0.4152410118609203f);
            const float sgn = (d & 1) ? 1.0f : -1.0f;
#pragma unroll
            for (int mt = 0; mt < 4; ++mt)
#pragma unroll
                for (int r = 0; r < 4; ++r) {
                    const int m = mbase + mt * 16 + quad * 4 + r;
                    const int b = m >> 11, s = m & 2047;
                    const float v = acc[mt][nt][r] + bv;
                    const float vp = __shfl_xor(v, 1);  // partner d^1 (lane^1)
                    float sn, cs;
                    sincosf((float)s * fr, &sn, &cs);
                    C[((size_t)(b * H_ + h) * S_ + s) * 128 + 64 + d] =
                        (bf16_t)(v * cs + sgn * vp * sn);
                }
        } else {  // EP == 3: V^T (B*H, 64, S)
            bf16_t* C = (bf16_t*)Cv;
            const int h = n >> 6, vd = n & 63;
#pragma unroll
            for (int mt = 0; mt < 4; ++mt) {
                const int s0 = mbase + mt * 16 + quad * 4;
                const int b = s0 >> 11, s = s0 & 2047;
                bf16x4 o = {(bf16_t)(acc[mt][nt][0] + bv), (bf16_t)(acc[mt][nt][1] + bv),
                            (bf16_t)(acc[mt][nt][2] + bv), (bf16_t)(acc[mt][nt][3] + bv)};
                *(bf16x4*)&C[((size_t)(b * H_ + h) * 64 + vd) * S_ + s] = o;
            }
        }
    }
}

// ---------------------------------------------------------------------------
// fp32 GEMM for k_r only (M=8192, N=64, K=2048): RoPE + broadcast to 16 heads.
// ---------------------------------------------------------------------------
__global__ __launch_bounds__(256) void gemm_kr(const float* __restrict__ A,
                                               const float* __restrict__ W,
                                               const float* __restrict__ bias,
                                               bf16_t* __restrict__ C,
                                               int M, int N, int K) {
    __shared__ float As[16][68];
    __shared__ float Bs[16][68];
    const int tid = threadIdx.x;
    const int tx = tid & 15, ty = tid >> 4;
    const int m0 = blockIdx.y * 64;
    const int arow = tid >> 2, acol = (tid & 3) << 2;
    const int brow = tid >> 4, bcol = (tid & 15) << 2;
    const float* Aptr = A + (size_t)(m0 + arow) * K + acol;
    const float* Bptr = W + (size_t)brow * N + bcol;
    float acc[4][4] = {};
    for (int k0 = 0; k0 < K; k0 += 16) {
        float4 av = *(const float4*)(Aptr + k0);
        float4 bv = *(const float4*)(Bptr + (size_t)k0 * N);
        __syncthreads();
        As[acol + 0][arow] = av.x;
        As[acol + 1][arow] = av.y;
        As[acol + 2][arow] = av.z;
        As[acol + 3][arow] = av.w;
        *(float4*)&Bs[brow][bcol] = bv;
        __syncthreads();
#pragma unroll
        for (int k = 0; k < 16; ++k) {
            float4 a4 = *(float4*)&As[k][ty << 2];
            float4 b4 = *(float4*)&Bs[k][tx << 2];
            float ar[4] = {a4.x, a4.y, a4.z, a4.w};
            float br[4] = {b4.x, b4.y, b4.z, b4.w};
#pragma unroll
            for (int i = 0; i < 4; ++i)
#pragma unroll
                for (int j = 0; j < 4; ++j)
                    acc[i][j] += ar[i] * br[j];
        }
    }
    const int gm = m0 + (ty << 2);
    const int d0 = tx << 2;
    const float b0 = bias[d0], b1 = bias[d0 + 1], b2 = bias[d0 + 2], b3 = bias[d0 + 3];
    const int ip0 = d0 >> 1, ip1 = ip0 + 1;
    const float fr0 = exp2f(-(float)ip0 * 0.4152410118609203f);
    const float fr1 = exp2f(-(float)ip1 * 0.4152410118609203f);
#pragma unroll
    for (int i = 0; i < 4; ++i) {
        const int m = gm + i;
        const int b = m >> 11, s = m & 2047;
        const float pos = (float)s;
        float sn0, cs0, sn1, cs1;
        sincosf(pos * fr0, &sn0, &cs0);
        sincosf(pos * fr1, &sn1, &cs1);
        const float x0 = acc[i][0] + b0, x1 = acc[i][1] + b1;
        const float x2 = acc[i][2] + b2, x3 = acc[i][3] + b3;
        bf16x4 o = {(bf16_t)(x0 * cs0 - x1 * sn0), (bf16_t)(x1 * cs0 + x0 * sn0),
                    (bf16_t)(x2 * cs1 - x3 * sn1), (bf16_t)(x3 * cs1 + x2 * sn1)};
        for (int h = 0; h < H_; ++h)
            *(bf16x4*)&C[((size_t)(b * H_ + h) * S_ + s) * 128 + 64 + d0] = o;
    }
}

// ---------------------------------------------------------------------------
// MFMA flash attention (unchanged from R2 except bf16 output).
// ---------------------------------------------------------------------------
__global__ __launch_bounds__(256) void flash_mfma(const bf16_t* __restrict__ Q,
                                                  const bf16_t* __restrict__ K,
                                                  const bf16_t* __restrict__ Vt,
                                                  bf16_t* __restrict__ O) {
    __shared__ bf16_t Ks[32][136];
    __shared__ bf16_t Vs[64][40];
    __shared__ bf16_t Ps[4][16][40];

    const int tid  = threadIdx.x;
    const int lane = tid & 63;
    const int wave = tid >> 6;
    const int n16  = lane & 15;
    const int quad = lane >> 4;
    const int bh   = blockIdx.y;
    const int q0   = blockIdx.x << 6;
    const int qbase = q0 + wave * 16;

    const bf16_t* Qg = Q + ((size_t)bh * S_ + qbase + n16) * 128;
    bf16x8 qf[4];
#pragma unroll
    for (int c = 0; c < 4; ++c)
        qf[c] = *(const bf16x8*)(Qg + c * 32 + quad * 8);

    const bf16_t* Kg = K + (size_t)bh * S_ * 128;
    const bf16_t* Vg = Vt + (size_t)bh * 64 * S_;

    f32x4 oacc[4] = {};
    float mrow[4] = {-3e30f, -3e30f, -3e30f, -3e30f};
    float lrow[4] = {};
    const float scale = 0.051776695296636886f;

    const int ktiles = (q0 >> 5) + 2;
    for (int t = 0; t < ktiles; ++t) {
        const int k0 = t << 5;
        __syncthreads();
#pragma unroll
        for (int c = 0; c < 2; ++c) {
            const int idx = tid + c * 256;
            const int r = idx >> 4, col = (idx & 15) << 3;
            *(bf16x8*)&Ks[r][col] = *(const bf16x8*)&Kg[(size_t)(k0 + r) * 128 + col];
        }
        {
            const int r = tid >> 2, col = (tid & 3) << 3;
            *(bf16x8*)&Vs[r][col] = *(const bf16x8*)&Vg[(size_t)r * S_ + k0 + col];
        }
        __syncthreads();

        f32x4 sacc0 = {}, sacc1 = {};
#pragma unroll
        for (int c = 0; c < 4; ++c) {
            bf16x8 kb0 = *(bf16x8*)&Ks[n16][c * 32 + quad * 8];
            bf16x8 kb1 = *(bf16x8*)&Ks[n16 + 16][c * 32 + quad * 8];
            sacc0 = mfma16(qf[c], kb0, sacc0);
            sacc1 = mfma16(qf[c], kb1, sacc1);
        }

        float p0[4], p1[4];
        const bool boundary = (k0 + 31 > qbase);
#pragma unroll
        for (int r = 0; r < 4; ++r) {
            float s0 = sacc0[r] * scale;
            float s1 = sacc1[r] * scale;
            if (boundary) {
                const int qrow = qbase + quad * 4 + r;
                if (k0 + n16 > qrow)      s0 = -3e30f;
                if (k0 + 16 + n16 > qrow) s1 = -3e30f;
            }
            p0[r] = s0;
            p1[r] = s1;
        }

        float alpha[4];
#pragma unroll
        for (int r = 0; r < 4; ++r) {
            float mx = fmaxf(p0[r], p1[r]);
            mx = fmaxf(mx, __shfl_xor(mx, 1));
            mx = fmaxf(mx, __shfl_xor(mx, 2));
            mx = fmaxf(mx, __shfl_xor(mx, 4));
            mx = fmaxf(mx, __shfl_xor(mx, 8));
            const float mn = fmaxf(mrow[r], mx);
            alpha[r] = __expf(mrow[r] - mn);
            mrow[r] = mn;
            const float e0 = __expf(p0[r] - mn);
            const float e1 = __expf(p1[r] - mn);
            p0[r] = e0;
            p1[r] = e1;
            float rs = e0 + e1;
            rs += __shfl_xor(rs, 1);
            rs += __shfl_xor(rs, 2);
            rs += __shfl_xor(rs, 4);
            rs += __shfl_xor(rs, 8);
            lrow[r] = lrow[r] * alpha[r] + rs;
        }
#pragma unroll
        for (int nt = 0; nt < 4; ++nt)
#pragma unroll
            for (int r = 0; r < 4; ++r)
                oacc[nt][r] *= alpha[r];

#pragma unroll
        for (int r = 0; r < 4; ++r) {
            Ps[wave][quad * 4 + r][n16]      = (bf16_t)p0[r];
            Ps[wave][quad * 4 + r][n16 + 16] = (bf16_t)p1[r];
        }
        bf16x8 pf = *(bf16x8*)&Ps[wave][n16][quad * 8];
#pragma unroll
        for (int nt = 0; nt < 4; ++nt) {
            bf16x8 vb = *(bf16x8*)&Vs[nt * 16 + n16][quad * 8];
            oacc[nt] = mfma16(pf, vb, oacc[nt]);
        }
    }

    float il[4];
#pragma unroll
    for (int r = 0; r < 4; ++r) il[r] = 1.0f / lrow[r];

    const int b = bh >> 4, h = bh & 15;
#pragma unroll
    for (int nt = 0; nt < 4; ++nt)
#pragma unroll
        for (int r = 0; r < 4; ++r)
            O[((size_t)b * S_ + qbase + quad * 4 + r) * (size_t)(H_ * 64)
              + h * 64 + nt * 16 + n16] = (bf16_t)(oacc[nt][r] * il[r]);
}

// ---------------------------------------------------------------------------
extern "C" void kernel_launch(void* const* d_in, const int* in_sizes, int n_in,
                              void* d_out, int out_size, void* d_ws, size_t ws_size,
                              hipStream_t stream) {
    const float* X     = (const float*)d_in[0];
    const float* W_dkv = (const float*)d_in[2];
    const float* b_dkv = (const float*)d_in[3];
    const float* W_dq  = (const float*)d_in[4];
    const float* b_dq  = (const float*)d_in[5];
    const float* W_uk  = (const float*)d_in[6];
    const float* b_uk  = (const float*)d_in[7];
    const float* W_uv  = (const float*)d_in[8];
    const float* b_uv  = (const float*)d_in[9];
    const float* W_uq  = (const float*)d_in[10];
    const float* b_uq  = (const float*)d_in[11];
    const float* W_qr  = (const float*)d_in[12];
    const float* b_qr  = (const float*)d_in[13];
    const float* W_kr  = (const float*)d_in[14];
    const float* b_kr  = (const float*)d_in[15];
    const float* W_fc  = (const float*)d_in[16];
    const float* b_fc  = (const float*)d_in[17];
    float* out = (float*)d_out;

    char* w = (char*)d_ws;
    bf16_t* Xb    = (bf16_t*)(w);                 // 8192x2048   33,554,432 B
    bf16_t* Wtdkv = (bf16_t*)(w + 33554432);      // 512x2048     2,097,152
    bf16_t* Wtdq  = (bf16_t*)(w + 35651584);      // 512x2048     2,097,152
    bf16_t* Wtuk  = (bf16_t*)(w + 37748736);      // 1024x512     1,048,576
    bf16_t* Wtuv  = (bf16_t*)(w + 38797312);      // 1024x512
    bf16_t* Wtuq  = (bf16_t*)(w + 39845888);      // 1024x512
    bf16_t* Wtqr  = (bf16_t*)(w + 40894464);      // 1024x512
    bf16_t* Wtfc  = (bf16_t*)(w + 41943040);      // 2048x1024    4,194,304
    bf16_t* ckv   = (bf16_t*)(w + 46137344);      // 8192x512     8,388,608
    bf16_t* cq    = (bf16_t*)(w + 54525952);      // 8192x512     8,388,608
    bf16_t* Qb    = (bf16_t*)(w + 62914560);      // (64,2048,128) 33,554,432
    bf16_t* Kb    = (bf16_t*)(w + 96468992);      // (64,2048,128) 33,554,432
    bf16_t* Vt    = (bf16_t*)(w + 130023424);     // (64,64,2048)  16,777,216
    bf16_t* attnb = (bf16_t*)(w + 146800640);     // 8192x1024    16,777,216

    const dim3 blk(256);
    // one-time casts / transposes
    cast_bf16<<<16384, blk, 0, stream>>>(X, Xb, 16777216);
    transpose_cast<<<dim3(16, 64), blk, 0, stream>>>(W_dkv, Wtdkv, 2048, 512);
    transpose_cast<<<dim3(16, 64), blk, 0, stream>>>(W_dq, Wtdq, 2048, 512);
    transpose_cast<<<dim3(32, 16), blk, 0, stream>>>(W_uk, Wtuk, 512, 1024);
    transpose_cast<<<dim3(32, 16), blk, 0, stream>>>(W_uv, Wtuv, 512, 1024);
    transpose_cast<<<dim3(32, 16), blk, 0, stream>>>(W_uq, Wtuq, 512, 1024);
    transpose_cast<<<dim3(32, 16), blk, 0, stream>>>(W_qr, Wtqr, 512, 1024);
    transpose_cast<<<dim3(64, 32), blk, 0, stream>>>(W_fc, Wtfc, 1024, 2048);
    // projections (all MFMA)
    mgemm<0><<<dim3(4, 64), blk, 0, stream>>>(Xb, Wtdkv, b_dkv, ckv, MTOK, 512, 2048);
    mgemm<0><<<dim3(4, 64), blk, 0, stream>>>(Xb, Wtdq, b_dq, cq, MTOK, 512, 2048);
    mgemm<1><<<dim3(8, 64), blk, 0, stream>>>(ckv, Wtuk, b_uk, Kb, MTOK, 1024, 512);
    mgemm<3><<<dim3(8, 64), blk, 0, stream>>>(ckv, Wtuv, b_uv, Vt, MTOK, 1024, 512);
    mgemm<1><<<dim3(8, 64), blk, 0, stream>>>(cq, Wtuq, b_uq, Qb, MTOK, 1024, 512);
    mgemm<2><<<dim3(8, 64), blk, 0, stream>>>(cq, Wtqr, b_qr, Qb, MTOK, 1024, 512);
    gemm_kr<<<dim3(1, 128), blk, 0, stream>>>(X, W_kr, b_kr, Kb, MTOK, 64, 2048);
    // attention + out-proj
    flash_mfma<<<dim3(32, 64), blk, 0, stream>>>(Qb, Kb, Vt, attnb);
    mgemm<5><<<dim3(16, 64), blk, 0, stream>>>(attnb, Wtfc, b_fc, out, MTOK, 2048, 1024);
}